// Round 5
// baseline (479.143 us; speedup 1.0000x reference)
//
#include <hip/hip_runtime.h>
#include <hip/hip_bf16.h>
#include <math.h>

#define DD 2048
#define MM 1024
#define KFREQ 128
#define TPB 256
#define POLY_KEEP 1024
#define MICRO_KEEP 512
#define BK 64
#define NT (DD / BK)
#define CCAP 256

typedef __bf16 bf16x8 __attribute__((ext_vector_type(8)));
typedef float f32x4 __attribute__((ext_vector_type(4)));
typedef const __attribute__((address_space(1))) void* gas_ptr;
typedef __attribute__((address_space(3))) void* las_ptr;

__device__ __forceinline__ void gl_lds16(const void* g, void* l) {
    __builtin_amdgcn_global_load_lds((gas_ptr)g, (las_ptr)l, 16, 0, 0);
}

__device__ __forceinline__ int SWZ(int i) { return i ^ ((i >> 4) & 15); }
__device__ __forceinline__ int BREV10(int i) { return (int)(__brev((unsigned)i) >> 22); }

// ---------- setup: masks + twiddles (32 blocks, 4-way split per d) ----------
__global__ __launch_bounds__(TPB) void k_prep(
    const float* __restrict__ poly_imp, const float* __restrict__ micro_imp,
    float* __restrict__ pmask, float* __restrict__ mmask, float2* __restrict__ tw) {
    __shared__ float sP[DD], sM[DD];
    __shared__ int sR[2][TPB];
    const int tid = threadIdx.x;
    for (int i = tid; i < DD; i += TPB) { sP[i] = poly_imp[i]; sM[i] = micro_imp[i]; }
    __syncthreads();
    const int dl = tid >> 2;
    const int d = blockIdx.x * 64 + dl;
    const int part = tid & 3;
    const float pv = sP[d], mv = sM[d];
    int rp = 0, rm = 0;
    for (int e = part * 512; e < part * 512 + 512; ++e) {
        float pe = sP[e], me = sM[e];
        rp += (int)((pe > pv) || (pe == pv && e < d));
        rm += (int)((me > mv) || (me == mv && e < d));
    }
    sR[0][tid] = rp; sR[1][tid] = rm;
    __syncthreads();
    if (part == 0) {
        int rpt = sR[0][tid] + sR[0][tid + 1] + sR[0][tid + 2] + sR[0][tid + 3];
        int rmt = sR[1][tid] + sR[1][tid + 1] + sR[1][tid + 2] + sR[1][tid + 3];
        pmask[d] = (rpt < POLY_KEEP) ? 1.f : 0.f;
        mmask[d] = (rmt < MICRO_KEEP) ? 1.f : 0.f;
    }
    if (tid < 64) {
        int i = blockIdx.x * 64 + tid;
        if (i == 0) tw[0] = make_float2(1.f, 0.f);
        else {
            int half = 1 << (31 - __clz(i));
            int p = i - half;
            double ang = M_PI * (double)p / (double)half;
            tw[i] = make_float2((float)cos(ang), (float)(-sin(ang)));
        }
    }
}

// ---------- setup: W_res -> bf16 ----------
__global__ void k_wcast(const float* __restrict__ W, __bf16* __restrict__ Wb) {
    int i = (blockIdx.x * blockDim.x + threadIdx.x) * 8;
    float4 a = *(const float4*)(W + i);
    float4 b = *(const float4*)(W + i + 4);
    bf16x8 o;
    o[0] = (__bf16)a.x; o[1] = (__bf16)a.y; o[2] = (__bf16)a.z; o[3] = (__bf16)a.w;
    o[4] = (__bf16)b.x; o[5] = (__bf16)b.y; o[6] = (__bf16)b.z; o[7] = (__bf16)b.w;
    *(bf16x8*)(Wb + i) = o;
}

// ---------- per-row, WAVE-LOCAL: LN -> rfft -> topk scale -> irfft -> poly/micro -> LN -> bf16 ----------
// One 64-lane wave per row; 16 complex values per lane in registers.
// Forward: DIF (natural in -> bit-reversed out): 6 shfl_xor stages (m=32..1), then 4 register stages.
// Inverse: DIT (bit-reversed in -> natural out): 4 register stages, then 6 shfl_xor stages.
// No __syncthreads anywhere.
__global__ __launch_bounds__(256, 4) void k_row(
    const float* __restrict__ x,
    const float* __restrict__ g_in, const float* __restrict__ b_in,
    const float* __restrict__ g_out, const float* __restrict__ b_out,
    const float* __restrict__ gains, const float* __restrict__ spec_bias,
    const float* __restrict__ coeffs,
    const float* __restrict__ mw1, const float* __restrict__ mb1,
    const float* __restrict__ mw2, const float* __restrict__ mb2,
    const float* __restrict__ pmask, const float* __restrict__ mmask,
    const float2* __restrict__ tw,
    __bf16* __restrict__ hf) {

    __shared__ float2 sZ[4][MM];          // 8 KB per wave slice

    const int tid = threadIdx.x;
    const int wid = tid >> 6;
    const int L = tid & 63;
    const int row = (blockIdx.x << 2) + wid;
    float2* Z = sZ[wid];
    unsigned long long* candKey = (unsigned long long*)&Z[0];   // 256 u64 (Z[0..255])
    float* scaleArr = (float*)&Z[256];                          // 1025 f32 (Z[256..769])

    const float* xr = x + (size_t)row * DD;
    const int d0 = L * 32;

    // ---- load 32 x-values + LN_in (wave reduce) ----
    float xv[32];
    #pragma unroll
    for (int q = 0; q < 8; ++q) {
        float4 t = *(const float4*)(xr + d0 + q * 4);
        xv[q * 4] = t.x; xv[q * 4 + 1] = t.y; xv[q * 4 + 2] = t.z; xv[q * 4 + 3] = t.w;
    }
    float s = 0.f, ss = 0.f;
    #pragma unroll
    for (int e = 0; e < 32; ++e) { s += xv[e]; ss += xv[e] * xv[e]; }
    #pragma unroll
    for (int o = 32; o; o >>= 1) { s += __shfl_xor(s, o); ss += __shfl_xor(ss, o); }
    const float mu = s * (1.f / DD);
    const float rstd = rsqrtf(ss * (1.f / DD) - mu * mu + 1e-5f);

    // z[n] = h[2n] + i h[2n+1], n = L*16 + j  (natural order, lane-contiguous)
    float zr[16], zi[16];
    #pragma unroll
    for (int q = 0; q < 8; ++q) {
        float4 g4 = *(const float4*)(g_in + d0 + q * 4);
        float4 b4 = *(const float4*)(b_in + d0 + q * 4);
        float v0 = (xv[q * 4]     - mu) * rstd * g4.x + b4.x;
        float v1 = (xv[q * 4 + 1] - mu) * rstd * g4.y + b4.y;
        float v2 = (xv[q * 4 + 2] - mu) * rstd * g4.z + b4.z;
        float v3 = (xv[q * 4 + 3] - mu) * rstd * g4.w + b4.w;
        zr[q * 2] = v0;     zi[q * 2] = v1;
        zr[q * 2 + 1] = v2; zi[q * 2 + 1] = v3;
    }

    // ---- forward FFT: DIF cross-lane stages (half = 512..16) ----
    #pragma unroll
    for (int st = 0; st < 6; ++st) {
        const int m = 32 >> st;
        const int half = m << 4;
        const bool hiS = (L & m) != 0;
        const int pbase = half + ((L & (m - 1)) << 4);
        #pragma unroll
        for (int j = 0; j < 16; ++j) {
            float tr = __shfl_xor(zr[j], m);
            float ti = __shfl_xor(zi[j], m);
            float2 w = tw[pbase + j];
            float dr = tr - zr[j], di = ti - zi[j];
            float hr = dr * w.x - di * w.y;
            float hi2 = dr * w.y + di * w.x;
            float lr = zr[j] + tr, li = zi[j] + ti;
            zr[j] = hiS ? hr : lr;
            zi[j] = hiS ? hi2 : li;
        }
    }
    // ---- forward FFT: in-register stages (half = 8,4,2,1) ----
    #pragma unroll
    for (int st = 0; st < 4; ++st) {
        const int h = 8 >> st;
        #pragma unroll
        for (int g0 = 0; g0 < 16; g0 += 2 * h) {
            #pragma unroll
            for (int p = 0; p < h; ++p) {
                const int i0 = g0 + p, i1 = i0 + h;
                float2 w = tw[h + p];
                float ar = zr[i0], ai = zi[i0], br = zr[i1], bi = zi[i1];
                float dr = ar - br, di = ai - bi;
                zr[i0] = ar + br; zi[i0] = ai + bi;
                zr[i1] = dr * w.x - di * w.y;
                zi[i1] = dr * w.y + di * w.x;
            }
        }
    }

    // ---- transpose: brev-order regs -> natural-order LDS ----
    #pragma unroll
    for (int j = 0; j < 16; ++j)
        Z[SWZ(BREV10(L * 16 + j))] = make_float2(zr[j], zi[j]);

    // ---- rfft unpack: X[k] for k = L + 64j, mags to regs ----
    float Xr[16], Xi[16];
    unsigned um[16];
    #pragma unroll
    for (int j = 0; j < 16; ++j) {
        int k = L + 64 * j;
        float2 a = Z[SWZ(k)];
        float2 b = Z[SWZ((MM - k) & (MM - 1))];
        float xer = 0.5f * (a.x + b.x), xei = 0.5f * (a.y - b.y);
        float xor_ = 0.5f * (a.y + b.y), xoi = 0.5f * (b.x - a.x);
        float2 w = tw[MM + k];
        Xr[j] = xer + w.x * xor_ - w.y * xoi;
        Xi[j] = xei + w.x * xoi + w.y * xor_;
        um[j] = __float_as_uint(Xr[j] * Xr[j] + Xi[j] * Xi[j]);
    }
    float nXr = 0.f;
    unsigned num_ = 0u;
    {
        float2 z0 = Z[SWZ(0)];
        float xn = z0.x - z0.y;                 // X[1024]
        if (L == 0) { nXr = xn; num_ = __float_as_uint(xn * xn); }
    }

    // ---- top-128 threshold: register binary search with ballot-count ----
    unsigned lo = 0u, hi = 0x7f800000u;
    for (int it = 0; it < 31 && lo < hi; ++it) {
        unsigned mid = lo + ((hi - lo + 1) >> 1);
        int c = (int)(num_ >= mid);
        #pragma unroll
        for (int j = 0; j < 16; ++j) c += (int)(um[j] >= mid);
        #pragma unroll
        for (int o = 32; o; o >>= 1) c += __shfl_xor(c, o);
        if (c >= KFREQ) lo = mid; else hi = mid - 1;
    }
    const unsigned V = lo;

    // ---- compaction: ballot-prefix into per-wave candidate list ----
    const unsigned long long ltmask = (1ull << L) - 1ull;
    int kcBase = 0;
    #pragma unroll
    for (int j = 0; j < 16; ++j) {
        bool p = (um[j] >= V);
        unsigned long long msk = __ballot(p);
        if (p) {
            int pos = kcBase + (int)__popcll(msk & ltmask);
            if (pos < CCAP)
                candKey[pos] = ((unsigned long long)um[j] << 32)
                             | (unsigned long long)(0xFFFFFFFFu - (unsigned)(L + 64 * j));
        }
        kcBase += (int)__popcll(msk);
    }
    {
        bool p = (num_ >= V);                    // only lane 0 can be true
        unsigned long long msk = __ballot(p);
        if (p && kcBase < CCAP)
            candKey[kcBase] = ((unsigned long long)num_ << 32)
                            | (unsigned long long)(0xFFFFFFFFu - 1024u);
        kcBase += (int)__popcll(msk);
    }
    const int kc = (kcBase < CCAP) ? kcBase : CCAP;

    // ---- zero scale array ----
    {
        float2* sc2 = (float2*)scaleArr;
        #pragma unroll
        for (int q = 0; q < 8; ++q) sc2[L * 8 + q] = make_float2(0.f, 0.f);
        if (L == 0) scaleArr[1024] = 0.f;
    }

    // ---- exact ranks among candidates (4 static slots/lane), scatter gains ----
    {
        const int s0 = L, s1 = L + 64, s2 = L + 128, s3 = L + 192;
        unsigned long long k0 = (s0 < kc) ? candKey[s0] : 0ull;
        unsigned long long k1 = (s1 < kc) ? candKey[s1] : 0ull;
        unsigned long long k2 = (s2 < kc) ? candKey[s2] : 0ull;
        unsigned long long k3 = (s3 < kc) ? candKey[s3] : 0ull;
        int r0 = 0, r1 = 0, r2 = 0, r3 = 0;
        for (int i = 0; i < kc; ++i) {
            unsigned long long ki = candKey[i];
            r0 += (int)(ki > k0); r1 += (int)(ki > k1);
            r2 += (int)(ki > k2); r3 += (int)(ki > k3);
        }
        if (s0 < kc) { unsigned kb = 0xFFFFFFFFu - (unsigned)k0; scaleArr[kb] = (r0 < KFREQ) ? gains[r0] : 0.f; }
        if (s1 < kc) { unsigned kb = 0xFFFFFFFFu - (unsigned)k1; scaleArr[kb] = (r1 < KFREQ) ? gains[r1] : 0.f; }
        if (s2 < kc) { unsigned kb = 0xFFFFFFFFu - (unsigned)k2; scaleArr[kb] = (r2 < KFREQ) ? gains[r2] : 0.f; }
        if (s3 < kc) { unsigned kb = 0xFFFFFFFFu - (unsigned)k3; scaleArr[kb] = (r3 < KFREQ) ? gains[r3] : 0.f; }
    }

    // ---- gather scales; scale X -> Y in place ----
    float scl[16];
    #pragma unroll
    for (int j = 0; j < 16; ++j) scl[j] = scaleArr[L + 64 * j];
    float Yn = 0.f;
    if (L == 0) Yn = scaleArr[1024] * nXr;
    #pragma unroll
    for (int j = 0; j < 16; ++j) { Xr[j] *= scl[j]; Xi[j] *= scl[j]; }

    // ---- Hermitian repack into ifft input z' (regs + lane shuffle) ----
    // partner of k=L+64j is 1024-k = (64-L) + 64*(15-j) for L>=1; lane0 local.
    {
        const int src = (64 - L) & 63;
        #pragma unroll
        for (int j = 0; j < 16; ++j) {
            int k = L + 64 * j;
            float Pr = __shfl(Xr[15 - j], src);
            float Pi = __shfl(Xi[15 - j], src);
            if (L == 0) {
                if (j == 0) { Pr = Yn; Pi = 0.f; }
                else        { Pr = Xr[16 - j]; Pi = Xi[16 - j]; }
            }
            // conj(Y[1024-k]) = (Pr, -Pi)
            float yer = 0.5f * (Xr[j] + Pr), yei = 0.5f * (Xi[j] - Pi);
            float tr  = 0.5f * (Xr[j] - Pr), ti  = 0.5f * (Xi[j] + Pi);
            float2 w = tw[MM + k];
            float yor = tr * w.x + ti * w.y;
            float yoi = ti * w.x - tr * w.y;
            zr[j] = yer - yoi;
            zi[j] = yei + yor;
        }
    }

    // ---- transpose: natural-order regs -> brev-order LDS -> DIT layout regs ----
    #pragma unroll
    for (int j = 0; j < 16; ++j)
        Z[SWZ(BREV10(L + 64 * j))] = make_float2(zr[j], zi[j]);
    #pragma unroll
    for (int j = 0; j < 16; ++j) {
        float2 v = Z[SWZ(L * 16 + j)];
        zr[j] = v.x; zi[j] = v.y;
    }

    // ---- inverse FFT: DIT in-register stages (half = 1,2,4,8), conj twiddles ----
    #pragma unroll
    for (int st = 0; st < 4; ++st) {
        const int h = 1 << st;
        #pragma unroll
        for (int g0 = 0; g0 < 16; g0 += 2 * h) {
            #pragma unroll
            for (int p = 0; p < h; ++p) {
                const int i0 = g0 + p, i1 = i0 + h;
                float2 w = tw[h + p];
                float ar = zr[i0], ai = zi[i0], br = zr[i1], bi = zi[i1];
                float mr = br * w.x + bi * w.y;        // b * conj(w)
                float mi = bi * w.x - br * w.y;
                zr[i0] = ar + mr; zi[i0] = ai + mi;
                zr[i1] = ar - mr; zi[i1] = ai - mi;
            }
        }
    }
    // ---- inverse FFT: DIT cross-lane stages (half = 16..512) ----
    #pragma unroll
    for (int st = 0; st < 6; ++st) {
        const int m = 1 << st;
        const int half = m << 4;
        const bool hiS = (L & m) != 0;
        const int pbase = half + ((L & (m - 1)) << 4);
        #pragma unroll
        for (int j = 0; j < 16; ++j) {
            float tr = __shfl_xor(zr[j], m);
            float ti = __shfl_xor(zi[j], m);
            float2 w = tw[pbase + j];
            float br = hiS ? zr[j] : tr;
            float bi = hiS ? zi[j] : ti;
            float mr = br * w.x + bi * w.y;            // b * conj(w)
            float mi = bi * w.x - br * w.y;
            float lr = zr[j] + mr, li = zi[j] + mi;    // low:  a=z
            float hr = tr - mr,    hi2 = ti - mi;      // high: a=t
            zr[j] = hiS ? hr : lr;
            zi[j] = hiS ? hi2 : li;
        }
    }

    // ---- poly + micro + LN_out (wave reduce), write bf16 ----
    const float c0 = coeffs[0], c1 = coeffs[1], c2 = coeffs[2];
    const float w1 = mw1[0], b1 = mb1[0], w2 = mw2[0], b2 = mb2[0];
    s = 0.f; ss = 0.f;
    #pragma unroll
    for (int q = 0; q < 8; ++q) {
        float4 sb = *(const float4*)(spec_bias + d0 + q * 4);
        float4 pm = *(const float4*)(pmask + d0 + q * 4);
        float4 mmv = *(const float4*)(mmask + d0 + q * 4);
        float vin[4] = { zr[q * 2], zi[q * 2], zr[q * 2 + 1], zi[q * 2 + 1] };
        float sbv[4] = { sb.x, sb.y, sb.z, sb.w };
        float pmv[4] = { pm.x, pm.y, pm.z, pm.w };
        float mmvv[4] = { mmv.x, mmv.y, mmv.z, mmv.w };
        float outv[4];
        #pragma unroll
        for (int e = 0; e < 4; ++e) {
            float t = vin[e] * (1.f / MM) + sbv[e];
            float xp = t;
            float acc = c0 * xp;
            xp *= t; acc += c1 * xp;
            xp *= t; acc += c2 * xp;
            float tp = (pmv[e] > 0.f) ? acc : t;
            float y = w1 * tp + b1;
            y = y / (1.f + __expf(-y));
            y = w2 * y + b2;
            y = y / (1.f + __expf(-y));
            float tm = (mmvv[e] > 0.f) ? y : tp;
            outv[e] = tm; s += tm; ss += tm * tm;
        }
        zr[q * 2] = outv[0];     zi[q * 2] = outv[1];
        zr[q * 2 + 1] = outv[2]; zi[q * 2 + 1] = outv[3];
    }
    #pragma unroll
    for (int o = 32; o; o >>= 1) { s += __shfl_xor(s, o); ss += __shfl_xor(ss, o); }
    {
        float mu2 = s * (1.f / DD);
        float rstd2 = rsqrtf(ss * (1.f / DD) - mu2 * mu2 + 1e-5f);
        #pragma unroll
        for (int v = 0; v < 4; ++v) {
            float4 ga = *(const float4*)(g_out + d0 + v * 8);
            float4 gb = *(const float4*)(g_out + d0 + v * 8 + 4);
            float4 ba = *(const float4*)(b_out + d0 + v * 8);
            float4 bb = *(const float4*)(b_out + d0 + v * 8 + 4);
            float gv[8] = { ga.x, ga.y, ga.z, ga.w, gb.x, gb.y, gb.z, gb.w };
            float bv[8] = { ba.x, ba.y, ba.z, ba.w, bb.x, bb.y, bb.z, bb.w };
            float tvv[8] = { zr[v * 4], zi[v * 4], zr[v * 4 + 1], zi[v * 4 + 1],
                             zr[v * 4 + 2], zi[v * 4 + 2], zr[v * 4 + 3], zi[v * 4 + 3] };
            bf16x8 o;
            #pragma unroll
            for (int e = 0; e < 8; ++e)
                o[e] = (__bf16)((tvv[e] - mu2) * rstd2 * gv[e] + bv[e]);
            *(bf16x8*)(hf + (size_t)row * DD + d0 + v * 8) = o;
        }
    }
}

// ---------- GEMM: 256x256 tile, 8-phase pipelined, bf16 MFMA (unchanged from R4) ----------
#define STAGE(G, ROW0, KB, LP) do {                                          \
    _Pragma("unroll")                                                        \
    for (int q_ = 0; q_ < 2; ++q_) {                                         \
        int qb_ = (q_ * 512 + (wid << 6)) * 8;                               \
        int pl_ = qb_ + lane * 8;                                            \
        int r_ = pl_ >> 6;                                                   \
        int c_ = (pl_ & 63) ^ (((r_ >> 1) & 7) << 3);                        \
        gl_lds16((G) + (size_t)((ROW0) + r_) * DD + (KB) + c_, (LP) + qb_);  \
    } } while (0)

#define LOADA(BUF, IH) do {                                                  \
    _Pragma("unroll")                                                        \
    for (int ii = 0; ii < 4; ++ii) {                                         \
        int rr = wm * 16 + ii * 32 + l15;                                    \
        int sw = ((rr >> 1) & 7) << 3;                                       \
        aR[ii][0] = *(const bf16x8*)&LA[BUF][IH][rr * 64 + ((l4 * 8) ^ sw)]; \
        aR[ii][1] = *(const bf16x8*)&LA[BUF][IH][rr * 64 + ((32 + l4 * 8) ^ sw)]; \
    } } while (0)

#define LOADB(BUF, JP, DST) do {                                             \
    _Pragma("unroll")                                                        \
    for (int jj = 0; jj < 2; ++jj) {                                         \
        int rr = wn * 16 + jj * 64 + l15;                                    \
        int sw = ((rr >> 1) & 7) << 3;                                       \
        DST[jj][0] = *(const bf16x8*)&LB[BUF][JP][rr * 64 + ((l4 * 8) ^ sw)]; \
        DST[jj][1] = *(const bf16x8*)&LB[BUF][JP][rr * 64 + ((32 + l4 * 8) ^ sw)]; \
    } } while (0)

#define MMAQ(IH, BP, JP) do {                                                \
    _Pragma("unroll")                                                        \
    for (int ii = 0; ii < 4; ++ii) {                                         \
        _Pragma("unroll")                                                    \
        for (int jj = 0; jj < 2; ++jj) {                                     \
            acc[(IH) * 4 + ii][(JP) * 2 + jj] = __builtin_amdgcn_mfma_f32_16x16x32_bf16( \
                aR[ii][0], BP[jj][0], acc[(IH) * 4 + ii][(JP) * 2 + jj], 0, 0, 0);       \
            acc[(IH) * 4 + ii][(JP) * 2 + jj] = __builtin_amdgcn_mfma_f32_16x16x32_bf16( \
                aR[ii][1], BP[jj][1], acc[(IH) * 4 + ii][(JP) * 2 + jj], 0, 0, 0);       \
        }                                                                    \
    } } while (0)

#define PH_PRE() do {                                                        \
    __builtin_amdgcn_sched_barrier(0);                                       \
    __builtin_amdgcn_s_barrier();                                            \
    __builtin_amdgcn_sched_barrier(0);                                       \
    __builtin_amdgcn_s_setprio(1); } while (0)

#define PH_POST() do {                                                       \
    __builtin_amdgcn_s_setprio(0);                                           \
    __builtin_amdgcn_sched_barrier(0);                                       \
    __builtin_amdgcn_s_barrier(); } while (0)

__global__ __launch_bounds__(512, 2) void k_gemm(
    const __bf16* __restrict__ A,
    const __bf16* __restrict__ Bt,
    const float* __restrict__ x,
    const float* __restrict__ b_res,
    const float* __restrict__ gate_p,
    float* __restrict__ out) {

    __shared__ __bf16 LA[2][2][128 * 64];
    __shared__ __bf16 LB[2][2][128 * 64];

    const int tid = threadIdx.x;
    const int lane = tid & 63;
    const int wid = tid >> 6;
    const int wm = wid >> 2;
    const int wn = wid & 3;
    const int l15 = lane & 15;
    const int l4 = lane >> 4;

    int orig = blockIdx.y * gridDim.x + blockIdx.x;
    int swz = (orig & 7) * 32 + (orig >> 3);
    const int m0 = (swz >> 3) * 256;
    const int n0 = (swz & 7) * 256;

    f32x4 acc[8][4] = {};
    bf16x8 aR[4][2], bR0[2][2], bR1[2][2];

    STAGE(A,  m0,       0, &LA[0][0][0]);
    STAGE(Bt, n0,       0, &LB[0][0][0]);
    STAGE(A,  m0 + 128, 0, &LA[0][1][0]);
    STAGE(Bt, n0 + 128, 0, &LB[0][1][0]);
    asm volatile("s_waitcnt vmcnt(4)" ::: "memory");
    STAGE(A,  m0,       BK, &LA[1][0][0]);
    STAGE(Bt, n0,       BK, &LB[1][0][0]);
    STAGE(A,  m0 + 128, BK, &LA[1][1][0]);
    asm volatile("s_waitcnt vmcnt(6)" ::: "memory");
    __builtin_amdgcn_s_barrier();

    for (int T = 0; T < NT; ++T) {
        const int buf = T & 1;
        const int kb1 = (T + 1) * BK;
        const int kb2 = (T + 2) * BK;

        LOADA(buf, 0);
        LOADB(buf, 0, bR0);
        if (T + 1 < NT) STAGE(Bt, n0 + 128, kb1, &LB[buf ^ 1][1][0]);
        PH_PRE();
        MMAQ(0, bR0, 0);
        PH_POST();

        LOADB(buf, 1, bR1);
        if (T + 2 < NT) STAGE(A, m0, kb2, &LA[buf][0][0]);
        PH_PRE();
        MMAQ(0, bR1, 1);
        PH_POST();

        LOADA(buf, 1);
        if (T + 2 < NT) STAGE(Bt, n0, kb2, &LB[buf][0][0]);
        PH_PRE();
        MMAQ(1, bR0, 0);
        PH_POST();

        if (T + 2 < NT) STAGE(A, m0 + 128, kb2, &LA[buf][1][0]);
        PH_PRE();
        MMAQ(1, bR1, 1);
        __builtin_amdgcn_s_setprio(0);
        __builtin_amdgcn_sched_barrier(0);
        if (T + 2 < NT) { asm volatile("s_waitcnt vmcnt(6)" ::: "memory"); }
        else            { asm volatile("s_waitcnt vmcnt(0)" ::: "memory"); }
        __builtin_amdgcn_s_barrier();
    }

    const float gate = gate_p[0];
    #pragma unroll
    for (int i = 0; i < 8; ++i) {
        int rowb = m0 + (i >> 2) * 128 + wm * 16 + (i & 3) * 32 + l4 * 4;
        #pragma unroll
        for (int j = 0; j < 4; ++j) {
            int col = n0 + (j >> 1) * 128 + wn * 16 + (j & 1) * 64 + l15;
            float br = b_res[col];
            #pragma unroll
            for (int r = 0; r < 4; ++r) {
                size_t off = (size_t)(rowb + r) * DD + col;
                out[off] = x[off] + gate * (acc[i][j][r] + br);
            }
        }
    }
}

extern "C" void kernel_launch(void* const* d_in, const int* in_sizes, int n_in,
                              void* d_out, int out_size, void* d_ws, size_t ws_size,
                              hipStream_t stream) {
    const float* x         = (const float*)d_in[0];
    const float* ln_in_g   = (const float*)d_in[1];
    const float* ln_in_b   = (const float*)d_in[2];
    const float* ln_out_g  = (const float*)d_in[3];
    const float* ln_out_b  = (const float*)d_in[4];
    const float* spec_gain = (const float*)d_in[5];
    const float* spec_bias = (const float*)d_in[6];
    const float* poly_c    = (const float*)d_in[7];
    const float* poly_imp  = (const float*)d_in[8];
    const float* micro_imp = (const float*)d_in[9];
    const float* mw1       = (const float*)d_in[10];
    const float* mb1       = (const float*)d_in[11];
    const float* mw2       = (const float*)d_in[12];
    const float* mb2       = (const float*)d_in[13];
    const float* W_res     = (const float*)d_in[14];
    const float* b_res     = (const float*)d_in[15];
    const float* gate      = (const float*)d_in[16];
    float* out = (float*)d_out;

    char* ws = (char*)d_ws;
    __bf16* hf    = (__bf16*)(ws);                       // 32 MiB
    __bf16* Wb    = (__bf16*)(ws + 33554432);            // 8 MiB
    float2* tw    = (float2*)(ws + 41943040);            // 16 KiB
    float*  pmask = (float*)(ws + 41959424);             // 8 KiB
    float*  mmask = (float*)(ws + 41967616);             // 8 KiB

    k_prep<<<dim3(32), dim3(TPB), 0, stream>>>(poly_imp, micro_imp, pmask, mmask, tw);
    k_wcast<<<dim3(2048), dim3(TPB), 0, stream>>>(W_res, Wb);
    k_row<<<dim3(2048), dim3(TPB), 0, stream>>>(x, ln_in_g, ln_in_b, ln_out_g, ln_out_b,
                                                spec_gain, spec_bias, poly_c,
                                                mw1, mb1, mw2, mb2,
                                                pmask, mmask, tw, hf);
    k_gemm<<<dim3(8, 32), dim3(512), 0, stream>>>(hf, Wb, x, b_res, gate, out);
}

// Round 8
// 434.485 us; speedup vs baseline: 1.1028x; 1.1028x over previous
//
#include <hip/hip_runtime.h>
#include <hip/hip_bf16.h>
#include <math.h>

#define DD 2048
#define MM 1024
#define KFREQ 128
#define TPB 256
#define POLY_KEEP 1024
#define MICRO_KEEP 512
#define BK 64
#define NT (DD / BK)
#define CCAP 256

typedef __bf16 bf16x8 __attribute__((ext_vector_type(8)));
typedef float f32x4 __attribute__((ext_vector_type(4)));
typedef const __attribute__((address_space(1))) void* gas_ptr;
typedef __attribute__((address_space(3))) void* las_ptr;

__device__ __forceinline__ void gl_lds16(const void* g, void* l) {
    __builtin_amdgcn_global_load_lds((gas_ptr)g, (las_ptr)l, 16, 0, 0);
}

__device__ __forceinline__ int SWZ(int i) { return i ^ ((i >> 4) & 15); }
__device__ __forceinline__ int BREV10(int i) { return (int)(__brev((unsigned)i) >> 22); }

// ---------- setup: masks + twiddles (32 blocks, 4-way split per d) ----------
__global__ __launch_bounds__(TPB) void k_prep(
    const float* __restrict__ poly_imp, const float* __restrict__ micro_imp,
    float* __restrict__ pmask, float* __restrict__ mmask, float2* __restrict__ tw) {
    __shared__ float sP[DD], sM[DD];
    __shared__ int sR[2][TPB];
    const int tid = threadIdx.x;
    for (int i = tid; i < DD; i += TPB) { sP[i] = poly_imp[i]; sM[i] = micro_imp[i]; }
    __syncthreads();
    const int dl = tid >> 2;
    const int d = blockIdx.x * 64 + dl;
    const int part = tid & 3;
    const float pv = sP[d], mv = sM[d];
    int rp = 0, rm = 0;
    for (int e = part * 512; e < part * 512 + 512; ++e) {
        float pe = sP[e], me = sM[e];
        rp += (int)((pe > pv) || (pe == pv && e < d));
        rm += (int)((me > mv) || (me == mv && e < d));
    }
    sR[0][tid] = rp; sR[1][tid] = rm;
    __syncthreads();
    if (part == 0) {
        int rpt = sR[0][tid] + sR[0][tid + 1] + sR[0][tid + 2] + sR[0][tid + 3];
        int rmt = sR[1][tid] + sR[1][tid + 1] + sR[1][tid + 2] + sR[1][tid + 3];
        pmask[d] = (rpt < POLY_KEEP) ? 1.f : 0.f;
        mmask[d] = (rmt < MICRO_KEEP) ? 1.f : 0.f;
    }
    if (tid < 64) {
        int i = blockIdx.x * 64 + tid;
        if (i == 0) tw[0] = make_float2(1.f, 0.f);
        else {
            int half = 1 << (31 - __clz(i));
            int p = i - half;
            double ang = M_PI * (double)p / (double)half;
            tw[i] = make_float2((float)cos(ang), (float)(-sin(ang)));
        }
    }
}

// ---------- setup: W_res -> bf16 ----------
__global__ void k_wcast(const float* __restrict__ W, __bf16* __restrict__ Wb) {
    int i = (blockIdx.x * blockDim.x + threadIdx.x) * 8;
    float4 a = *(const float4*)(W + i);
    float4 b = *(const float4*)(W + i + 4);
    bf16x8 o;
    o[0] = (__bf16)a.x; o[1] = (__bf16)a.y; o[2] = (__bf16)a.z; o[3] = (__bf16)a.w;
    o[4] = (__bf16)b.x; o[5] = (__bf16)b.y; o[6] = (__bf16)b.z; o[7] = (__bf16)b.w;
    *(bf16x8*)(Wb + i) = o;
}

// ---------- per-row, WAVE-LOCAL: LN -> rfft -> topk scale -> irfft -> poly/micro -> LN -> bf16 ----------
// One 64-lane wave per row; 16 complex values per lane in registers.
// __launch_bounds__(256,2): 256-VGPR budget -- R5's (256,4) capped at 128 and spilled
// (WRITE_SIZE 343 MB of scratch). Peak live set ~90-150 regs incl. hoisted tw loads.
__global__ __launch_bounds__(256, 2) void k_row(
    const float* __restrict__ x,
    const float* __restrict__ g_in, const float* __restrict__ b_in,
    const float* __restrict__ g_out, const float* __restrict__ b_out,
    const float* __restrict__ gains, const float* __restrict__ spec_bias,
    const float* __restrict__ coeffs,
    const float* __restrict__ mw1, const float* __restrict__ mb1,
    const float* __restrict__ mw2, const float* __restrict__ mb2,
    const float* __restrict__ pmask, const float* __restrict__ mmask,
    const float2* __restrict__ tw,
    __bf16* __restrict__ hf) {

    __shared__ float2 sZ[4][MM];          // 8 KB per wave slice

    const int tid = threadIdx.x;
    const int wid = tid >> 6;
    const int L = tid & 63;
    const int row = (blockIdx.x << 2) + wid;
    float2* Z = sZ[wid];
    unsigned long long* candKey = (unsigned long long*)&Z[0];   // 256 u64 (Z[0..255])
    float* scaleArr = (float*)&Z[256];                          // 1025 f32 (Z[256..769])

    const float* xr = x + (size_t)row * DD;
    const int d0 = L * 32;

    // ---- load 32 x-values + LN_in (wave reduce) ----
    float xv[32];
    #pragma unroll
    for (int q = 0; q < 8; ++q) {
        float4 t = *(const float4*)(xr + d0 + q * 4);
        xv[q * 4] = t.x; xv[q * 4 + 1] = t.y; xv[q * 4 + 2] = t.z; xv[q * 4 + 3] = t.w;
    }
    float s = 0.f, ss = 0.f;
    #pragma unroll
    for (int e = 0; e < 32; ++e) { s += xv[e]; ss += xv[e] * xv[e]; }
    #pragma unroll
    for (int o = 32; o; o >>= 1) { s += __shfl_xor(s, o); ss += __shfl_xor(ss, o); }
    const float mu = s * (1.f / DD);
    const float rstd = rsqrtf(ss * (1.f / DD) - mu * mu + 1e-5f);

    // z[n] = h[2n] + i h[2n+1], n = L*16 + j  (natural order, lane-contiguous)
    float zr[16], zi[16];
    #pragma unroll
    for (int q = 0; q < 8; ++q) {
        float4 g4 = *(const float4*)(g_in + d0 + q * 4);
        float4 b4 = *(const float4*)(b_in + d0 + q * 4);
        zr[q * 2]     = (xv[q * 4]     - mu) * rstd * g4.x + b4.x;
        zi[q * 2]     = (xv[q * 4 + 1] - mu) * rstd * g4.y + b4.y;
        zr[q * 2 + 1] = (xv[q * 4 + 2] - mu) * rstd * g4.z + b4.z;
        zi[q * 2 + 1] = (xv[q * 4 + 3] - mu) * rstd * g4.w + b4.w;
    }

    // ---- forward FFT: DIF cross-lane stages (half = 512..16) ----
    #pragma unroll
    for (int st = 0; st < 6; ++st) {
        const int m = 32 >> st;
        const int half = m << 4;
        const bool hiS = (L & m) != 0;
        const int pbase = half + ((L & (m - 1)) << 4);
        #pragma unroll
        for (int j = 0; j < 16; ++j) {
            float tr = __shfl_xor(zr[j], m);
            float ti = __shfl_xor(zi[j], m);
            float2 w = tw[pbase + j];
            float dr = tr - zr[j], di = ti - zi[j];
            float hr = dr * w.x - di * w.y;
            float hi2 = dr * w.y + di * w.x;
            float lr = zr[j] + tr, li = zi[j] + ti;
            zr[j] = hiS ? hr : lr;
            zi[j] = hiS ? hi2 : li;
        }
    }
    // ---- forward FFT: in-register stages (half = 8,4,2,1) ----
    #pragma unroll
    for (int st = 0; st < 4; ++st) {
        const int h = 8 >> st;
        #pragma unroll
        for (int g0 = 0; g0 < 16; g0 += 2 * h) {
            #pragma unroll
            for (int p = 0; p < h; ++p) {
                const int i0 = g0 + p, i1 = i0 + h;
                float2 w = tw[h + p];
                float ar = zr[i0], ai = zi[i0], br = zr[i1], bi = zi[i1];
                float dr = ar - br, di = ai - bi;
                zr[i0] = ar + br; zi[i0] = ai + bi;
                zr[i1] = dr * w.x - di * w.y;
                zi[i1] = dr * w.y + di * w.x;
            }
        }
    }

    // ---- transpose: brev-order regs -> natural-order LDS ----
    #pragma unroll
    for (int j = 0; j < 16; ++j)
        Z[SWZ(BREV10(L * 16 + j))] = make_float2(zr[j], zi[j]);

    // ---- rfft unpack: X[k] for k = L + 64j, mags to regs ----
    float Xr[16], Xi[16];
    unsigned um[16];
    #pragma unroll
    for (int j = 0; j < 16; ++j) {
        int k = L + 64 * j;
        float2 a = Z[SWZ(k)];
        float2 b = Z[SWZ((MM - k) & (MM - 1))];
        float xer = 0.5f * (a.x + b.x), xei = 0.5f * (a.y - b.y);
        float xor_ = 0.5f * (a.y + b.y), xoi = 0.5f * (b.x - a.x);
        float2 w = tw[MM + k];
        Xr[j] = xer + w.x * xor_ - w.y * xoi;
        Xi[j] = xei + w.x * xoi + w.y * xor_;
        um[j] = __float_as_uint(Xr[j] * Xr[j] + Xi[j] * Xi[j]);
    }
    float nXr = 0.f;
    unsigned num_ = 0u;
    {
        float2 z0 = Z[SWZ(0)];
        float xn = z0.x - z0.y;                 // X[1024]
        if (L == 0) { nXr = xn; num_ = __float_as_uint(xn * xn); }
    }

    // ---- top-128 threshold: register binary search with wave-count ----
    unsigned lo = 0u, hi = 0x7f800000u;
    for (int it = 0; it < 31 && lo < hi; ++it) {
        unsigned mid = lo + ((hi - lo + 1) >> 1);
        int c = (int)(num_ >= mid);
        #pragma unroll
        for (int j = 0; j < 16; ++j) c += (int)(um[j] >= mid);
        #pragma unroll
        for (int o = 32; o; o >>= 1) c += __shfl_xor(c, o);
        if (c >= KFREQ) lo = mid; else hi = mid - 1;
    }
    const unsigned V = lo;

    // ---- compaction: ballot-prefix into per-wave candidate list ----
    const unsigned long long ltmask = (1ull << L) - 1ull;
    int kcBase = 0;
    #pragma unroll
    for (int j = 0; j < 16; ++j) {
        bool p = (um[j] >= V);
        unsigned long long msk = __ballot(p);
        if (p) {
            int pos = kcBase + (int)__popcll(msk & ltmask);
            if (pos < CCAP)
                candKey[pos] = ((unsigned long long)um[j] << 32)
                             | (unsigned long long)(0xFFFFFFFFu - (unsigned)(L + 64 * j));
        }
        kcBase += (int)__popcll(msk);
    }
    {
        bool p = (num_ >= V);                    // only lane 0 can be true
        unsigned long long msk = __ballot(p);
        if (p && kcBase < CCAP)
            candKey[kcBase] = ((unsigned long long)num_ << 32)
                            | (unsigned long long)(0xFFFFFFFFu - 1024u);
        kcBase += (int)__popcll(msk);
    }
    const int kc = (kcBase < CCAP) ? kcBase : CCAP;

    // ---- zero scale array ----
    {
        float2* sc2 = (float2*)scaleArr;
        #pragma unroll
        for (int q = 0; q < 8; ++q) sc2[L * 8 + q] = make_float2(0.f, 0.f);
        if (L == 0) scaleArr[1024] = 0.f;
    }

    // ---- exact ranks among candidates (4 static slots/lane), scatter gains ----
    {
        const int s0 = L, s1 = L + 64, s2 = L + 128, s3 = L + 192;
        unsigned long long k0 = (s0 < kc) ? candKey[s0] : 0ull;
        unsigned long long k1 = (s1 < kc) ? candKey[s1] : 0ull;
        unsigned long long k2 = (s2 < kc) ? candKey[s2] : 0ull;
        unsigned long long k3 = (s3 < kc) ? candKey[s3] : 0ull;
        int r0 = 0, r1 = 0, r2 = 0, r3 = 0;
        for (int i = 0; i < kc; ++i) {
            unsigned long long ki = candKey[i];
            r0 += (int)(ki > k0); r1 += (int)(ki > k1);
            r2 += (int)(ki > k2); r3 += (int)(ki > k3);
        }
        if (s0 < kc) { unsigned kb = 0xFFFFFFFFu - (unsigned)k0; scaleArr[kb] = (r0 < KFREQ) ? gains[r0] : 0.f; }
        if (s1 < kc) { unsigned kb = 0xFFFFFFFFu - (unsigned)k1; scaleArr[kb] = (r1 < KFREQ) ? gains[r1] : 0.f; }
        if (s2 < kc) { unsigned kb = 0xFFFFFFFFu - (unsigned)k2; scaleArr[kb] = (r2 < KFREQ) ? gains[r2] : 0.f; }
        if (s3 < kc) { unsigned kb = 0xFFFFFFFFu - (unsigned)k3; scaleArr[kb] = (r3 < KFREQ) ? gains[r3] : 0.f; }
    }

    // ---- gather scales (folded multiply, no scl[] array) ----
    #pragma unroll
    for (int j = 0; j < 16; ++j) {
        float sc = scaleArr[L + 64 * j];
        Xr[j] *= sc; Xi[j] *= sc;
    }
    float Yn = 0.f;
    if (L == 0) Yn = scaleArr[1024] * nXr;

    // ---- Hermitian repack into ifft input z' (regs + lane shuffle) ----
    {
        const int src = (64 - L) & 63;
        #pragma unroll
        for (int j = 0; j < 16; ++j) {
            int k = L + 64 * j;
            float Pr = __shfl(Xr[15 - j], src);
            float Pi = __shfl(Xi[15 - j], src);
            if (L == 0) {
                if (j == 0) { Pr = Yn; Pi = 0.f; }
                else        { Pr = Xr[16 - j]; Pi = Xi[16 - j]; }
            }
            float yer = 0.5f * (Xr[j] + Pr), yei = 0.5f * (Xi[j] - Pi);
            float tr  = 0.5f * (Xr[j] - Pr), ti  = 0.5f * (Xi[j] + Pi);
            float2 w = tw[MM + k];
            float yor = tr * w.x + ti * w.y;
            float yoi = ti * w.x - tr * w.y;
            zr[j] = yer - yoi;
            zi[j] = yei + yor;
        }
    }

    // ---- transpose: natural-order regs -> brev-order LDS -> DIT layout regs ----
    #pragma unroll
    for (int j = 0; j < 16; ++j)
        Z[SWZ(BREV10(L + 64 * j))] = make_float2(zr[j], zi[j]);
    #pragma unroll
    for (int j = 0; j < 16; ++j) {
        float2 v = Z[SWZ(L * 16 + j)];
        zr[j] = v.x; zi[j] = v.y;
    }

    // ---- inverse FFT: DIT in-register stages (half = 1,2,4,8), conj twiddles ----
    #pragma unroll
    for (int st = 0; st < 4; ++st) {
        const int h = 1 << st;
        #pragma unroll
        for (int g0 = 0; g0 < 16; g0 += 2 * h) {
            #pragma unroll
            for (int p = 0; p < h; ++p) {
                const int i0 = g0 + p, i1 = i0 + h;
                float2 w = tw[h + p];
                float ar = zr[i0], ai = zi[i0], br = zr[i1], bi = zi[i1];
                float mr = br * w.x + bi * w.y;
                float mi = bi * w.x - br * w.y;
                zr[i0] = ar + mr; zi[i0] = ai + mi;
                zr[i1] = ar - mr; zi[i1] = ai - mi;
            }
        }
    }
    // ---- inverse FFT: DIT cross-lane stages (half = 16..512) ----
    #pragma unroll
    for (int st = 0; st < 6; ++st) {
        const int m = 1 << st;
        const int half = m << 4;
        const bool hiS = (L & m) != 0;
        const int pbase = half + ((L & (m - 1)) << 4);
        #pragma unroll
        for (int j = 0; j < 16; ++j) {
            float tr = __shfl_xor(zr[j], m);
            float ti = __shfl_xor(zi[j], m);
            float2 w = tw[pbase + j];
            float br = hiS ? zr[j] : tr;
            float bi = hiS ? zi[j] : ti;
            float mr = br * w.x + bi * w.y;
            float mi = bi * w.x - br * w.y;
            float lr = zr[j] + mr, li = zi[j] + mi;
            float hr = tr - mr,    hi2 = ti - mi;
            zr[j] = hiS ? hr : lr;
            zi[j] = hiS ? hi2 : li;
        }
    }

    // ---- poly + micro + LN_out (wave reduce), write bf16 ----
    const float c0 = coeffs[0], c1 = coeffs[1], c2 = coeffs[2];
    const float w1 = mw1[0], b1 = mb1[0], w2 = mw2[0], b2 = mb2[0];
    s = 0.f; ss = 0.f;
    #pragma unroll
    for (int q = 0; q < 8; ++q) {
        float4 sb = *(const float4*)(spec_bias + d0 + q * 4);
        float4 pm = *(const float4*)(pmask + d0 + q * 4);
        float4 mmv = *(const float4*)(mmask + d0 + q * 4);
        float vin[4] = { zr[q * 2], zi[q * 2], zr[q * 2 + 1], zi[q * 2 + 1] };
        float sbv[4] = { sb.x, sb.y, sb.z, sb.w };
        float pmv[4] = { pm.x, pm.y, pm.z, pm.w };
        float mmvv[4] = { mmv.x, mmv.y, mmv.z, mmv.w };
        float outv[4];
        #pragma unroll
        for (int e = 0; e < 4; ++e) {
            float t = vin[e] * (1.f / MM) + sbv[e];
            float xp = t;
            float acc = c0 * xp;
            xp *= t; acc += c1 * xp;
            xp *= t; acc += c2 * xp;
            float tp = (pmv[e] > 0.f) ? acc : t;
            float y = w1 * tp + b1;
            y = y / (1.f + __expf(-y));
            y = w2 * y + b2;
            y = y / (1.f + __expf(-y));
            float tm = (mmvv[e] > 0.f) ? y : tp;
            outv[e] = tm; s += tm; ss += tm * tm;
        }
        zr[q * 2] = outv[0];     zi[q * 2] = outv[1];
        zr[q * 2 + 1] = outv[2]; zi[q * 2 + 1] = outv[3];
    }
    #pragma unroll
    for (int o = 32; o; o >>= 1) { s += __shfl_xor(s, o); ss += __shfl_xor(ss, o); }
    {
        float mu2 = s * (1.f / DD);
        float rstd2 = rsqrtf(ss * (1.f / DD) - mu2 * mu2 + 1e-5f);
        #pragma unroll
        for (int v = 0; v < 4; ++v) {
            float4 ga = *(const float4*)(g_out + d0 + v * 8);
            float4 gb = *(const float4*)(g_out + d0 + v * 8 + 4);
            float4 ba = *(const float4*)(b_out + d0 + v * 8);
            float4 bb = *(const float4*)(b_out + d0 + v * 8 + 4);
            float gv[8] = { ga.x, ga.y, ga.z, ga.w, gb.x, gb.y, gb.z, gb.w };
            float bv[8] = { ba.x, ba.y, ba.z, ba.w, bb.x, bb.y, bb.z, bb.w };
            float tvv[8] = { zr[v * 4], zi[v * 4], zr[v * 4 + 1], zi[v * 4 + 1],
                             zr[v * 4 + 2], zi[v * 4 + 2], zr[v * 4 + 3], zi[v * 4 + 3] };
            bf16x8 o;
            #pragma unroll
            for (int e = 0; e < 8; ++e)
                o[e] = (__bf16)((tvv[e] - mu2) * rstd2 * gv[e] + bv[e]);
            *(bf16x8*)(hf + (size_t)row * DD + d0 + v * 8) = o;
        }
    }
}

// ---------- GEMM: 256x256 tile, 8-phase pipelined, bf16 MFMA (unchanged from R4) ----------
#define STAGE(G, ROW0, KB, LP) do {                                          \
    _Pragma("unroll")                                                        \
    for (int q_ = 0; q_ < 2; ++q_) {                                         \
        int qb_ = (q_ * 512 + (wid << 6)) * 8;                               \
        int pl_ = qb_ + lane * 8;                                            \
        int r_ = pl_ >> 6;                                                   \
        int c_ = (pl_ & 63) ^ (((r_ >> 1) & 7) << 3);                        \
        gl_lds16((G) + (size_t)((ROW0) + r_) * DD + (KB) + c_, (LP) + qb_);  \
    } } while (0)

#define LOADA(BUF, IH) do {                                                  \
    _Pragma("unroll")                                                        \
    for (int ii = 0; ii < 4; ++ii) {                                         \
        int rr = wm * 16 + ii * 32 + l15;                                    \
        int sw = ((rr >> 1) & 7) << 3;                                       \
        aR[ii][0] = *(const bf16x8*)&LA[BUF][IH][rr * 64 + ((l4 * 8) ^ sw)]; \
        aR[ii][1] = *(const bf16x8*)&LA[BUF][IH][rr * 64 + ((32 + l4 * 8) ^ sw)]; \
    } } while (0)

#define LOADB(BUF, JP, DST) do {                                             \
    _Pragma("unroll")                                                        \
    for (int jj = 0; jj < 2; ++jj) {                                         \
        int rr = wn * 16 + jj * 64 + l15;                                    \
        int sw = ((rr >> 1) & 7) << 3;                                       \
        DST[jj][0] = *(const bf16x8*)&LB[BUF][JP][rr * 64 + ((l4 * 8) ^ sw)]; \
        DST[jj][1] = *(const bf16x8*)&LB[BUF][JP][rr * 64 + ((32 + l4 * 8) ^ sw)]; \
    } } while (0)

#define MMAQ(IH, BP, JP) do {                                                \
    _Pragma("unroll")                                                        \
    for (int ii = 0; ii < 4; ++ii) {                                         \
        _Pragma("unroll")                                                    \
        for (int jj = 0; jj < 2; ++jj) {                                     \
            acc[(IH) * 4 + ii][(JP) * 2 + jj] = __builtin_amdgcn_mfma_f32_16x16x32_bf16( \
                aR[ii][0], BP[jj][0], acc[(IH) * 4 + ii][(JP) * 2 + jj], 0, 0, 0);       \
            acc[(IH) * 4 + ii][(JP) * 2 + jj] = __builtin_amdgcn_mfma_f32_16x16x32_bf16( \
                aR[ii][1], BP[jj][1], acc[(IH) * 4 + ii][(JP) * 2 + jj], 0, 0, 0);       \
        }                                                                    \
    } } while (0)

#define PH_PRE() do {                                                        \
    __builtin_amdgcn_sched_barrier(0);                                       \
    __builtin_amdgcn_s_barrier();                                            \
    __builtin_amdgcn_sched_barrier(0);                                       \
    __builtin_amdgcn_s_setprio(1); } while (0)

#define PH_POST() do {                                                       \
    __builtin_amdgcn_s_setprio(0);                                           \
    __builtin_amdgcn_sched_barrier(0);                                       \
    __builtin_amdgcn_s_barrier(); } while (0)

__global__ __launch_bounds__(512, 2) void k_gemm(
    const __bf16* __restrict__ A,
    const __bf16* __restrict__ Bt,
    const float* __restrict__ x,
    const float* __restrict__ b_res,
    const float* __restrict__ gate_p,
    float* __restrict__ out) {

    __shared__ __bf16 LA[2][2][128 * 64];
    __shared__ __bf16 LB[2][2][128 * 64];

    const int tid = threadIdx.x;
    const int lane = tid & 63;
    const int wid = tid >> 6;
    const int wm = wid >> 2;
    const int wn = wid & 3;
    const int l15 = lane & 15;
    const int l4 = lane >> 4;

    int orig = blockIdx.y * gridDim.x + blockIdx.x;
    int swz = (orig & 7) * 32 + (orig >> 3);
    const int m0 = (swz >> 3) * 256;
    const int n0 = (swz & 7) * 256;

    f32x4 acc[8][4] = {};
    bf16x8 aR[4][2], bR0[2][2], bR1[2][2];

    STAGE(A,  m0,       0, &LA[0][0][0]);
    STAGE(Bt, n0,       0, &LB[0][0][0]);
    STAGE(A,  m0 + 128, 0, &LA[0][1][0]);
    STAGE(Bt, n0 + 128, 0, &LB[0][1][0]);
    asm volatile("s_waitcnt vmcnt(4)" ::: "memory");
    STAGE(A,  m0,       BK, &LA[1][0][0]);
    STAGE(Bt, n0,       BK, &LB[1][0][0]);
    STAGE(A,  m0 + 128, BK, &LA[1][1][0]);
    asm volatile("s_waitcnt vmcnt(6)" ::: "memory");
    __builtin_amdgcn_s_barrier();

    for (int T = 0; T < NT; ++T) {
        const int buf = T & 1;
        const int kb1 = (T + 1) * BK;
        const int kb2 = (T + 2) * BK;

        LOADA(buf, 0);
        LOADB(buf, 0, bR0);
        if (T + 1 < NT) STAGE(Bt, n0 + 128, kb1, &LB[buf ^ 1][1][0]);
        PH_PRE();
        MMAQ(0, bR0, 0);
        PH_POST();

        LOADB(buf, 1, bR1);
        if (T + 2 < NT) STAGE(A, m0, kb2, &LA[buf][0][0]);
        PH_PRE();
        MMAQ(0, bR1, 1);
        PH_POST();

        LOADA(buf, 1);
        if (T + 2 < NT) STAGE(Bt, n0, kb2, &LB[buf][0][0]);
        PH_PRE();
        MMAQ(1, bR0, 0);
        PH_POST();

        if (T + 2 < NT) STAGE(A, m0 + 128, kb2, &LA[buf][1][0]);
        PH_PRE();
        MMAQ(1, bR1, 1);
        __builtin_amdgcn_s_setprio(0);
        __builtin_amdgcn_sched_barrier(0);
        if (T + 2 < NT) { asm volatile("s_waitcnt vmcnt(6)" ::: "memory"); }
        else            { asm volatile("s_waitcnt vmcnt(0)" ::: "memory"); }
        __builtin_amdgcn_s_barrier();
    }

    const float gate = gate_p[0];
    #pragma unroll
    for (int i = 0; i < 8; ++i) {
        int rowb = m0 + (i >> 2) * 128 + wm * 16 + (i & 3) * 32 + l4 * 4;
        #pragma unroll
        for (int j = 0; j < 4; ++j) {
            int col = n0 + (j >> 1) * 128 + wn * 16 + (j & 1) * 64 + l15;
            float br = b_res[col];
            #pragma unroll
            for (int r = 0; r < 4; ++r) {
                size_t off = (size_t)(rowb + r) * DD + col;
                out[off] = x[off] + gate * (acc[i][j][r] + br);
            }
        }
    }
}

extern "C" void kernel_launch(void* const* d_in, const int* in_sizes, int n_in,
                              void* d_out, int out_size, void* d_ws, size_t ws_size,
                              hipStream_t stream) {
    const float* x         = (const float*)d_in[0];
    const float* ln_in_g   = (const float*)d_in[1];
    const float* ln_in_b   = (const float*)d_in[2];
    const float* ln_out_g  = (const float*)d_in[3];
    const float* ln_out_b  = (const float*)d_in[4];
    const float* spec_gain = (const float*)d_in[5];
    const float* spec_bias = (const float*)d_in[6];
    const float* poly_c    = (const float*)d_in[7];
    const float* poly_imp  = (const float*)d_in[8];
    const float* micro_imp = (const float*)d_in[9];
    const float* mw1       = (const float*)d_in[10];
    const float* mb1       = (const float*)d_in[11];
    const float* mw2       = (const float*)d_in[12];
    const float* mb2       = (const float*)d_in[13];
    const float* W_res     = (const float*)d_in[14];
    const float* b_res     = (const float*)d_in[15];
    const float* gate      = (const float*)d_in[16];
    float* out = (float*)d_out;

    char* ws = (char*)d_ws;
    __bf16* hf    = (__bf16*)(ws);                       // 32 MiB
    __bf16* Wb    = (__bf16*)(ws + 33554432);            // 8 MiB
    float2* tw    = (float2*)(ws + 41943040);            // 16 KiB
    float*  pmask = (float*)(ws + 41959424);             // 8 KiB
    float*  mmask = (float*)(ws + 41967616);             // 8 KiB

    k_prep<<<dim3(32), dim3(TPB), 0, stream>>>(poly_imp, micro_imp, pmask, mmask, tw);
    k_wcast<<<dim3(2048), dim3(TPB), 0, stream>>>(W_res, Wb);
    k_row<<<dim3(2048), dim3(TPB), 0, stream>>>(x, ln_in_g, ln_in_b, ln_out_g, ln_out_b,
                                                spec_gain, spec_bias, poly_c,
                                                mw1, mb1, mw2, mb2,
                                                pmask, mmask, tw, hf);
    k_gemm<<<dim3(8, 32), dim3(512), 0, stream>>>(hf, Wb, x, b_res, gate, out);
}